// Round 18
// baseline (1397.436 us; speedup 1.0000x reference)
//
#include <hip/hip_runtime.h>
#include <math.h>

#define TT 2048
#define HH 64
#define NE 4       // batch elems per block
#define NBLK 128   // 512 / NE
#define NTHR 512   // 8 waves: 0-3 = L0 (j=wv), 4-7 = L1 (j=wv-4)

typedef _Float16 half8 __attribute__((ext_vector_type(8)));
typedef float f32x4 __attribute__((ext_vector_type(4)));

__device__ __forceinline__ float sigmoid_fast(float x) {
    float e = __expf(-x);
    return __builtin_amdgcn_rcpf(1.0f + e);
}
__device__ __forceinline__ float tanh_fast(float x) {
    float e = __expf(-2.0f * x);
    return fmaf(2.0f, __builtin_amdgcn_rcpf(1.0f + e), -1.0f);
}

// Round 18: partial-skew rebalance of r17 (one barrier/step kept).
// r17 decode: step ~1310cy vs ~455cy issue -> chain-dominated; L1's 4-deep
// MFMA chain + L0/L1 imbalance (8 vs 16 MFMAs) on the critical path.
// Change: L0 waves also compute partial(t-1) = Wih1 . h0(t-1) (they already
// hold the h0 frags; wf slots 4g+2,3 were ZERO, now Wih1) -> publish f32
// C-frags to pglds. L1 skews to gates1(t-2): acc INIT from partial(t-2)
// (read crosses one barrier -> latency hidden) + 8 Whh1 MFMAs, 2-deep.
// Every MFMA chain now depth 2; L1's h0-frag reads vanish; waves balanced.
// Partial passes through LDS as exact f32 in the same accumulation order ->
// absmax must stay 4.882812e-4 EXACTLY (correctness check for the skew).
// + s_setprio(1) around MFMA clusters (role-diverse waves, T5 regime).
// Schedule: step t: L0: gates0(t), partial(t-1)->pglds[t&1]; h0(t)->hsw[0][rp^1].
//           L1: gates1(t-2) = pglds[rp^1] + Whh1.h1(t-3) (hsw[1][rp^1]);
//               h1(t-2)->hsw[1][rp]. Loop t=0..TT+1; h_last in hsw[1][1].
__global__ __launch_bounds__(NTHR) __attribute__((amdgpu_waves_per_eu(4, 4)))
void lstm_skew_kernel(const float* __restrict__ x,      // [B,T]
                      const float* __restrict__ w_ih0,  // [256,1]
                      const float* __restrict__ w_hh0,  // [256,64]
                      const float* __restrict__ b_ih0,  // [256]
                      const float* __restrict__ b_hh0,  // [256]
                      const float* __restrict__ w_ih1,  // [256,64]
                      const float* __restrict__ w_hh1,  // [256,64]
                      const float* __restrict__ b_ih1,  // [256]
                      const float* __restrict__ b_hh1,  // [256]
                      const float* __restrict__ w1, const float* __restrict__ b1,
                      const float* __restrict__ w2, const float* __restrict__ b2,
                      const float* __restrict__ w3, const float* __restrict__ b3,
                      float* __restrict__ out)          // [B,10]
{
    const int tid = threadIdx.x;
    const int wv  = tid >> 6;        // wave 0..7
    const int l   = tid & 63;
    const int L   = wv >> 2;         // layer this wave owns
    const int j   = wv & 3;          // unit group [16j, 16j+16)
    const int e16 = l & 15;          // MFMA col (elem; valid < NE)
    const int kg  = l >> 4;          // k-group / C row-quad
    const int bA  = blockIdx.x * NE;

    __shared__ __align__(16) float xs[(TT + 2) * (NE + 1)];    // [t][5] pad, 2 tail rows
    __shared__ __align__(16) float glds[2][4][NE][72];         // [L][g][e][u pad]
    __shared__ __align__(16) float pglds[2][4][NE][72];        // [parity][g][e][u pad]
    __shared__ __align__(16) _Float16 hsw[2][2][16 * 64];      // [L][parity] swizzled
    __shared__ float cls1[NE][HH];
    __shared__ float cls2[NE][32];

    // zero h buffers + pglds (t<2 garbage suppression)
    for (int i = tid; i < 2 * 2 * 16 * 64; i += NTHR)
        ((_Float16*)hsw)[i] = (_Float16)0.0f;
    for (int i = tid; i < 2 * 4 * NE * 72; i += NTHR)
        ((float*)pglds)[i] = 0.0f;
    // stage x: xs[t*5+e] (stride-5 conflict-free); pad t=TT, TT+1 with 0
    for (int i = tid; i < NE * TT; i += NTHR) {
        const int e = i >> 11, t = i & (TT - 1);
        xs[t * (NE + 1) + e] = x[(size_t)(bA + e) * TT + t];
    }
    for (int i = tid; i < 2 * (NE + 1); i += NTHR)
        xs[TT * (NE + 1) + i] = 0.0f;

    // ---- weight A-frags (fp16), 16-slot layout ----
    // L0: wf[4g+0,1] = Whh0(g,j) kc0,1 ; wf[4g+2,3] = Wih1(g,j) kc0,1
    // L1: wf[4g+0,1] = Whh1(g,j) kc0,1 ; wf[4g+2,3] = ZERO (unused)
    half8 wf[16];
    {
        auto frag = [&](const float* M, int g, int kc) {
            const int row = g * 64 + 16 * j + e16;   // A-frag row = l&15
            half8 v;
            #pragma unroll
            for (int i = 0; i < 8; ++i) v[i] = (_Float16)M[row * HH + kc * 32 + kg * 8 + i];
            return v;
        };
        const float* M01 = L ? w_hh1 : w_hh0;
        #pragma unroll
        for (int g = 0; g < 4; ++g) {
            wf[4 * g + 0] = frag(M01, g, 0);
            wf[4 * g + 1] = frag(M01, g, 1);
            if (!L) {
                wf[4 * g + 2] = frag(w_ih1, g, 0);
                wf[4 * g + 3] = frag(w_ih1, g, 1);
            } else {
                half8 zz;
                #pragma unroll
                for (int i = 0; i < 8; ++i) zz[i] = (_Float16)0.0f;
                wf[4 * g + 2] = zz;
                wf[4 * g + 3] = zz;
            }
        }
    }

    // ---- act identity: lane owns (L, unit au, elem ae) ----
    const int au = 16 * j + (l >> 2);    // unit, within wave's own group
    const int ae = l & 3;                // elem
    float bi[4], wxr[4];
    {
        const float* bihp = L ? b_ih1 : b_ih0;
        const float* bhhp = L ? b_hh1 : b_hh0;
        #pragma unroll
        for (int g = 0; g < 4; ++g) {
            bi[g]  = bihp[g * 64 + au] + bhhp[g * 64 + au];
            wxr[g] = L ? 0.0f : w_ih0[g * 64 + au];
        }
    }
    // pin (rounds 1-4 lesson: allocator rematerializes weight loads otherwise)
    #pragma unroll
    for (int i = 0; i < 16; ++i) asm volatile("" : "+v"(wf[i]));
    #pragma unroll
    for (int g = 0; g < 4; ++g) {
        asm volatile("" : "+v"(bi[g]));
        asm volatile("" : "+v"(wxr[g]));
    }

    float c = 0.0f;                      // lane's cell state (unit au, elem ae)

    // Broadcast-aliased frag/partial addresses (r17): cols >=4 read col 0.
    const int e4   = (e16 < NE) ? e16 : 0;
    const int swz4 = (e4 & 7) << 4;
    const int hro0 = e4 * 128 + ((16 * kg) ^ swz4);          // k-chunk 0
    const int hro1 = e4 * 128 + ((64 + 16 * kg) ^ swz4);     // k-chunk 1
    const int hwb  = ae * 128 + ((2 * au) ^ (ae << 4));      // act h write byte
    const int u0   = 16 * j + 4 * kg;
    const f32x4 z4 = {0.0f, 0.0f, 0.0f, 0.0f};

    __syncthreads();

    for (int t = 0; t <= TT + 1; ++t) {
        const int rp = t & 1;
        f32x4 acc[4];
        if (!L) {
            // ---- L0: gates0(t) + partial(t-1), both 2-deep chains ----
            const char* h0r = (const char*)&hsw[0][rp][0];   // h0(t-1)
            half8 f0 = *(const half8*)(h0r + hro0);
            half8 f1 = *(const half8*)(h0r + hro1);
            f32x4 par[4];
            __builtin_amdgcn_s_setprio(1);
            #pragma unroll
            for (int g = 0; g < 4; ++g) {
                acc[g] = __builtin_amdgcn_mfma_f32_16x16x32_f16(wf[4 * g + 0], f0, z4, 0, 0, 0);
                par[g] = __builtin_amdgcn_mfma_f32_16x16x32_f16(wf[4 * g + 2], f0, z4, 0, 0, 0);
                acc[g] = __builtin_amdgcn_mfma_f32_16x16x32_f16(wf[4 * g + 1], f1, acc[g], 0, 0, 0);
                par[g] = __builtin_amdgcn_mfma_f32_16x16x32_f16(wf[4 * g + 3], f1, par[g], 0, 0, 0);
            }
            __builtin_amdgcn_s_setprio(0);
            if (e16 < NE) {
                #pragma unroll
                for (int g = 0; g < 4; ++g) {
                    *(f32x4*)&glds[0][g][e16][u0] = acc[g];
                    *(f32x4*)&pglds[rp][g][e16][u0] = par[g];
                }
            }
        } else {
            // ---- L1: gates1(t-2) = partial(t-2) + Whh1 . h1(t-3), 2-deep ----
            const char* h1r = (const char*)&hsw[1][rp ^ 1][0];   // h1(t-3)
            half8 f2 = *(const half8*)(h1r + hro0);
            half8 f3 = *(const half8*)(h1r + hro1);
            #pragma unroll
            for (int g = 0; g < 4; ++g)
                acc[g] = *(const f32x4*)&pglds[rp ^ 1][g][e4][u0];   // partial(t-2)
            __builtin_amdgcn_s_setprio(1);
            #pragma unroll
            for (int g = 0; g < 4; ++g) {
                acc[g] = __builtin_amdgcn_mfma_f32_16x16x32_f16(wf[4 * g + 0], f2, acc[g], 0, 0, 0);
                acc[g] = __builtin_amdgcn_mfma_f32_16x16x32_f16(wf[4 * g + 1], f3, acc[g], 0, 0, 0);
            }
            __builtin_amdgcn_s_setprio(0);
            if (e16 < NE) {
                #pragma unroll
                for (int g = 0; g < 4; ++g)
                    *(f32x4*)&glds[1][g][e16][u0] = acc[g];
            }
        }
        // ---- same-wave readback + act (1 unit-elem/lane, 10 trans) ----
        {
            float z0 = glds[L][0][ae][au];
            float z1 = glds[L][1][ae][au];
            float z2 = glds[L][2][ae][au];
            float z3 = glds[L][3][ae][au];
            const float xt = xs[t * (NE + 1) + ae];
            z0 += fmaf(wxr[0], xt, bi[0]);
            z1 += fmaf(wxr[1], xt, bi[1]);
            z2 += fmaf(wxr[2], xt, bi[2]);
            z3 += fmaf(wxr[3], xt, bi[3]);
            float gi = sigmoid_fast(z0);
            float gf = sigmoid_fast(z1);
            float gg = tanh_fast(z2);
            float go = sigmoid_fast(z3);
            c = fmaf(gf, c, gi * gg);
            float h = go * tanh_fast(c);
            if (L && t <= 1) { c = 0.0f; h = 0.0f; }   // h1(s<0) = 0
            // L0 writes h0(t) -> parity rp^1 ; L1 writes h1(t-2) -> parity rp
            char* hw = (char*)&hsw[L][L ? rp : (rp ^ 1)][0];
            *(_Float16*)(hw + hwb) = (_Float16)h;
        }
        __syncthreads();
    }
    // h_last = h1(TT-1), written at t=TT+1 (odd) -> hsw[1][1]

    // ---- classifier head: wave wv<4 handles elem wv ----
    if (wv < 4) {
        const char* h1f = (const char*)&hsw[1][1][0];
        float a = b1[l];
        #pragma unroll 8
        for (int k = 0; k < HH; ++k) {
            const float hk = (float)*(const _Float16*)(h1f + wv * 128 + ((2 * k) ^ (wv << 4)));
            a = fmaf(w1[l * HH + k], hk, a);
        }
        cls1[wv][l] = fmaxf(a, 0.0f);
    }
    __syncthreads();
    if (wv < 4 && l < 32) {
        float a = b2[l];
        #pragma unroll 8
        for (int k = 0; k < HH; ++k) a = fmaf(w2[l * HH + k], cls1[wv][k], a);
        cls2[wv][l] = fmaxf(a, 0.0f);
    }
    __syncthreads();
    if (wv < 4 && l < 10) {
        float a = b3[l];
        #pragma unroll
        for (int k = 0; k < 32; ++k) a = fmaf(w3[l * 32 + k], cls2[wv][k], a);
        out[(size_t)(bA + wv) * 10 + l] = a;
    }
}

extern "C" void kernel_launch(void* const* d_in, const int* in_sizes, int n_in,
                              void* d_out, int out_size, void* d_ws, size_t ws_size,
                              hipStream_t stream) {
    const float* x     = (const float*)d_in[0];
    const float* w_ih0 = (const float*)d_in[1];
    const float* w_hh0 = (const float*)d_in[2];
    const float* b_ih0 = (const float*)d_in[3];
    const float* b_hh0 = (const float*)d_in[4];
    const float* w_ih1 = (const float*)d_in[5];
    const float* w_hh1 = (const float*)d_in[6];
    const float* b_ih1 = (const float*)d_in[7];
    const float* b_hh1 = (const float*)d_in[8];
    const float* w1    = (const float*)d_in[9];
    const float* b1    = (const float*)d_in[10];
    const float* w2    = (const float*)d_in[11];
    const float* b2    = (const float*)d_in[12];
    const float* w3    = (const float*)d_in[13];
    const float* b3    = (const float*)d_in[14];
    float* out = (float*)d_out;

    lstm_skew_kernel<<<NBLK, NTHR, 0, stream>>>(x, w_ih0, w_hh0, b_ih0, b_hh0,
                                                w_ih1, w_hh1, b_ih1, b_hh1,
                                                w1, b1, w2, b2, w3, b3, out);
}

// Round 19
// 856.627 us; speedup vs baseline: 1.6313x; 1.6313x over previous
//
#include <hip/hip_runtime.h>
#include <math.h>

#define TT 2048
#define HH 64
#define NE 4       // batch elems per block
#define NBLK 128   // 512 / NE
#define NTHR 512   // 8 waves: (L = wv>>2, j = wv&3)

typedef _Float16 half8 __attribute__((ext_vector_type(8)));
typedef float f32x4 __attribute__((ext_vector_type(4)));

__device__ __forceinline__ float sigmoid_fast(float x) {
    float e = __expf(-x);
    return __builtin_amdgcn_rcpf(1.0f + e);
}
__device__ __forceinline__ float tanh_fast(float x) {
    float e = __expf(-2.0f * x);
    return fmaf(2.0f, __builtin_amdgcn_rcpf(1.0f + e), -1.0f);
}
// select element r (runtime, per-lane-constant) from f32x4 via 3 cndmask —
// static element indices only (rule #20: no scratch).
__device__ __forceinline__ float sel4(f32x4 v, int r) {
    float s01 = (r & 1) ? v[1] : v[0];
    float s23 = (r & 1) ? v[3] : v[2];
    return (r & 2) ? s23 : s01;
}

// Round 19: in-register gate consumption — NO LDS round-trip for gates.
// r17 layout kept (one barrier/step, L0=8/L1=16 MFMAs, 1122us best), but the
// B-frag column alias changes from "cols>=4 -> col 0" to "col c -> elem c&3":
// the wave's 16 C-columns now hold elems {0..3} x4 copies, so lane (kg,e16)
// activates its OWN (unit = 16j+4kg+(e16>>2), elem = e16&3) straight from
// acc[g][e16>>2] — 10 trans/lane, perfect 64-lane coverage, and the glds
// C-write + readback (8 stores + 4 loads + full LDS latency on the serial
// chain, r18 lesson: LDS hops dominate) is DELETED. Used columns are
// bit-identical to r17's -> absmax must stay 4.882812e-4 exactly.
__global__ __launch_bounds__(NTHR) __attribute__((amdgpu_waves_per_eu(4, 4)))
void lstm_direct_kernel(const float* __restrict__ x,      // [B,T]
                        const float* __restrict__ w_ih0,  // [256,1]
                        const float* __restrict__ w_hh0,  // [256,64]
                        const float* __restrict__ b_ih0,  // [256]
                        const float* __restrict__ b_hh0,  // [256]
                        const float* __restrict__ w_ih1,  // [256,64]
                        const float* __restrict__ w_hh1,  // [256,64]
                        const float* __restrict__ b_ih1,  // [256]
                        const float* __restrict__ b_hh1,  // [256]
                        const float* __restrict__ w1, const float* __restrict__ b1,
                        const float* __restrict__ w2, const float* __restrict__ b2,
                        const float* __restrict__ w3, const float* __restrict__ b3,
                        float* __restrict__ out)          // [B,10]
{
    const int tid = threadIdx.x;
    const int wv  = tid >> 6;        // wave 0..7
    const int l   = tid & 63;
    const int L   = wv >> 2;         // layer this wave owns
    const int j   = wv & 3;          // unit group [16j, 16j+16)
    const int e16 = l & 15;          // MFMA col
    const int kg  = l >> 4;          // k-group / C row-quad
    const int bA  = blockIdx.x * NE;

    __shared__ __align__(16) float xs[(TT + 1) * (NE + 1)];    // [t][5] pad
    __shared__ __align__(16) _Float16 hsw[2][2][16 * 64];      // [L][parity] swizzled
    __shared__ float cls1[NE][HH];
    __shared__ float cls2[NE][32];

    // zero h buffers (rows 4..15 written by dup lanes, benign)
    for (int i = tid; i < 2 * 2 * 16 * 64; i += NTHR)
        ((_Float16*)hsw)[i] = (_Float16)0.0f;
    // stage x: xs[t*5+e] (stride-5 conflict-free), coalesced reads; pad t=TT
    for (int i = tid; i < NE * TT; i += NTHR) {
        const int e = i >> 11, t = i & (TT - 1);
        xs[t * (NE + 1) + e] = x[(size_t)(bA + e) * TT + t];
    }
    if (tid < NE + 1) xs[TT * (NE + 1) + tid] = 0.0f;

    // ---- weight A-frags (fp16), 16-slot layout (r17) ----
    // wf[4g+0,1] = (L ? Wih1 : Whh0)(g,j) kc=0,1
    // wf[4g+2,3] = L ? Whh1(g,j) kc=0,1 : ZERO (unused by L0 exec path)
    half8 wf[16];
    {
        auto frag = [&](const float* M, int g, int kc) {
            const int row = g * 64 + 16 * j + e16;   // A-frag row = l&15
            half8 v;
            #pragma unroll
            for (int i = 0; i < 8; ++i) v[i] = (_Float16)M[row * HH + kc * 32 + kg * 8 + i];
            return v;
        };
        const float* M01 = L ? w_ih1 : w_hh0;
        #pragma unroll
        for (int g = 0; g < 4; ++g) {
            wf[4 * g + 0] = frag(M01, g, 0);
            wf[4 * g + 1] = frag(M01, g, 1);
            if (L) {
                wf[4 * g + 2] = frag(w_hh1, g, 0);
                wf[4 * g + 3] = frag(w_hh1, g, 1);
            } else {
                half8 zz;
                #pragma unroll
                for (int i = 0; i < 8; ++i) zz[i] = (_Float16)0.0f;
                wf[4 * g + 2] = zz;
                wf[4 * g + 3] = zz;
            }
        }
    }

    // ---- act identity: lane owns (L, unit au, elem ae) IN-REGISTER ----
    const int rsel = e16 >> 2;           // C-row quad-offset this lane consumes
    const int au = 16 * j + 4 * kg + rsel;
    const int ae = e16 & 3;              // elem (= aliased B column content)
    float bi[4], wxr[4];
    {
        const float* bihp = L ? b_ih1 : b_ih0;
        const float* bhhp = L ? b_hh1 : b_hh0;
        #pragma unroll
        for (int g = 0; g < 4; ++g) {
            bi[g]  = bihp[g * 64 + au] + bhhp[g * 64 + au];
            wxr[g] = L ? 0.0f : w_ih0[g * 64 + au];
        }
    }
    // pin (rounds 1-4 lesson: allocator rematerializes weight loads otherwise)
    #pragma unroll
    for (int i = 0; i < 16; ++i) asm volatile("" : "+v"(wf[i]));
    #pragma unroll
    for (int g = 0; g < 4; ++g) {
        asm volatile("" : "+v"(bi[g]));
        asm volatile("" : "+v"(wxr[g]));
    }

    float c = 0.0f;                      // lane's cell state (unit au, elem ae)

    // B-frag address: col c reads elem c&3 (4-way duplicate columns)
    const int swz4 = (ae & 7) << 4;
    const int hro0 = ae * 128 + ((16 * kg) ^ swz4);          // k-chunk 0
    const int hro1 = ae * 128 + ((64 + 16 * kg) ^ swz4);     // k-chunk 1
    const int hwb  = ae * 128 + ((2 * au) ^ (ae << 4));      // act h write byte
    const f32x4 z4 = {0.0f, 0.0f, 0.0f, 0.0f};

    __syncthreads();

    for (int t = 0; t <= TT; ++t) {
        const int rp = t & 1;            // read parity
        // ---- MFMA: gates(L==0: gates0(t); L==1: gates1(t-1)), raw ----
        f32x4 acc[4];
        if (L) {
            const char* h0r = (const char*)&hsw[0][rp][0];
            const char* h1r = (const char*)&hsw[1][rp][0];
            half8 f0 = *(const half8*)(h0r + hro0);
            half8 f1 = *(const half8*)(h0r + hro1);
            half8 f2 = *(const half8*)(h1r + hro0);
            half8 f3 = *(const half8*)(h1r + hro1);
            #pragma unroll
            for (int g = 0; g < 4; ++g) {
                acc[g] = __builtin_amdgcn_mfma_f32_16x16x32_f16(wf[4 * g + 0], f0, z4, 0, 0, 0);
                acc[g] = __builtin_amdgcn_mfma_f32_16x16x32_f16(wf[4 * g + 1], f1, acc[g], 0, 0, 0);
                acc[g] = __builtin_amdgcn_mfma_f32_16x16x32_f16(wf[4 * g + 2], f2, acc[g], 0, 0, 0);
                acc[g] = __builtin_amdgcn_mfma_f32_16x16x32_f16(wf[4 * g + 3], f3, acc[g], 0, 0, 0);
            }
        } else {
            const char* h0r = (const char*)&hsw[0][rp][0];
            half8 f0 = *(const half8*)(h0r + hro0);
            half8 f1 = *(const half8*)(h0r + hro1);
            #pragma unroll
            for (int g = 0; g < 4; ++g) {
                acc[g] = __builtin_amdgcn_mfma_f32_16x16x32_f16(wf[4 * g + 0], f0, z4, 0, 0, 0);
                acc[g] = __builtin_amdgcn_mfma_f32_16x16x32_f16(wf[4 * g + 1], f1, acc[g], 0, 0, 0);
            }
        }
        // ---- act directly from registers (1 unit-elem/lane, 10 trans) ----
        {
            float z0 = sel4(acc[0], rsel);
            float z1 = sel4(acc[1], rsel);
            float z2 = sel4(acc[2], rsel);
            float z3 = sel4(acc[3], rsel);
            const float xt = xs[t * (NE + 1) + ae];
            z0 += fmaf(wxr[0], xt, bi[0]);
            z1 += fmaf(wxr[1], xt, bi[1]);
            z2 += fmaf(wxr[2], xt, bi[2]);
            z3 += fmaf(wxr[3], xt, bi[3]);
            float gi = sigmoid_fast(z0);
            float gf = sigmoid_fast(z1);
            float gg = tanh_fast(z2);
            float go = sigmoid_fast(z3);
            c = fmaf(gf, c, gi * gg);
            float h = go * tanh_fast(c);
            if (L && t == 0) { c = 0.0f; h = 0.0f; }   // enforce h1(-1)=0
            *(_Float16*)((char*)&hsw[L][rp ^ 1][0] + hwb) = (_Float16)h;
        }
        __syncthreads();
    }
    // h_last = h1(TT-1), written at t=TT into parity (TT&1)^1 = 1

    // ---- classifier head: wave wv<4 handles elem wv ----
    if (wv < 4) {
        const char* h1f = (const char*)&hsw[1][1][0];
        float a = b1[l];
        #pragma unroll 8
        for (int k = 0; k < HH; ++k) {
            const float hk = (float)*(const _Float16*)(h1f + wv * 128 + ((2 * k) ^ (wv << 4)));
            a = fmaf(w1[l * HH + k], hk, a);
        }
        cls1[wv][l] = fmaxf(a, 0.0f);
    }
    __syncthreads();
    if (wv < 4 && l < 32) {
        float a = b2[l];
        #pragma unroll 8
        for (int k = 0; k < HH; ++k) a = fmaf(w2[l * HH + k], cls1[wv][k], a);
        cls2[wv][l] = fmaxf(a, 0.0f);
    }
    __syncthreads();
    if (wv < 4 && l < 10) {
        float a = b3[l];
        #pragma unroll
        for (int k = 0; k < 32; ++k) a = fmaf(w3[l * 32 + k], cls2[wv][k], a);
        out[(size_t)(bA + wv) * 10 + l] = a;
    }
}

extern "C" void kernel_launch(void* const* d_in, const int* in_sizes, int n_in,
                              void* d_out, int out_size, void* d_ws, size_t ws_size,
                              hipStream_t stream) {
    const float* x     = (const float*)d_in[0];
    const float* w_ih0 = (const float*)d_in[1];
    const float* w_hh0 = (const float*)d_in[2];
    const float* b_ih0 = (const float*)d_in[3];
    const float* b_hh0 = (const float*)d_in[4];
    const float* w_ih1 = (const float*)d_in[5];
    const float* w_hh1 = (const float*)d_in[6];
    const float* b_ih1 = (const float*)d_in[7];
    const float* b_hh1 = (const float*)d_in[8];
    const float* w1    = (const float*)d_in[9];
    const float* b1    = (const float*)d_in[10];
    const float* w2    = (const float*)d_in[11];
    const float* b2    = (const float*)d_in[12];
    const float* w3    = (const float*)d_in[13];
    const float* b3    = (const float*)d_in[14];
    float* out = (float*)d_out;

    lstm_direct_kernel<<<NBLK, NTHR, 0, stream>>>(x, w_ih0, w_hh0, b_ih0, b_hh0,
                                                  w_ih1, w_hh1, b_ih1, b_hh1,
                                                  w1, b1, w2, b2, w3, b3, out);
}